// Round 15
// baseline (366.037 us; speedup 1.0000x reference)
//
#include <hip/hip_runtime.h>
#include <cfloat>
#include <cstdint>
#include <climits>

// Problem constants (YOLOv8 640x640 head)
#define NB 64
#define NG 32
#define NC 80
#define NA 8400
#define KTOP 13
#define CHUNKF 512             // fusedAB chunk (2 anchors/thread)
#define NCHF 17                // ceil(NA/CHUNKF)
#define NCAND (NCHF * KTOP)    // 221 candidates per (b,g)
#define CHUNK 256              // phaseC chunk (unchanged)
#define NCH 33                 // phaseC grid.x (unchanged)
#define GGRP 16                // g's per LDS group (2 groups of 16)

// lex compare-exchange, descending (key desc, idx asc on ties) — branchless
#define CE(ka, ia, kb, ib)                                            \
    {                                                                 \
        const bool sw = (ka < kb) || (ka == kb && ia > ib);           \
        const unsigned tk = sw ? kb : ka;                             \
        const int      ti = sw ? ib : ia;                             \
        kb = sw ? ka : kb;  ib = sw ? ia : ib;                        \
        ka = tk;            ia = ti;                                  \
    }

// Wave64 max-reduce on the VALU pipe via DPP. Signed i32 max: positive-float
// bits are monotone positive ints, -FLT_MAX negative, bound_ctrl=true injects
// 0 (never wins while a positive key exists). HW-verified R1..R14 (absmax 0).
__device__ __forceinline__ int wave_max_pos(int m) {
    m = max(m, __builtin_amdgcn_update_dpp(0, m, 0x111, 0xF, 0xF, true)); // row_shr:1
    m = max(m, __builtin_amdgcn_update_dpp(0, m, 0x112, 0xF, 0xF, true)); // row_shr:2
    m = max(m, __builtin_amdgcn_update_dpp(0, m, 0x114, 0xF, 0xF, true)); // row_shr:4
    m = max(m, __builtin_amdgcn_update_dpp(0, m, 0x118, 0xF, 0xF, true)); // row_shr:8
    m = max(m, __builtin_amdgcn_update_dpp(0, m, 0x142, 0xF, 0xF, true)); // row_bcast:15
    m = max(m, __builtin_amdgcn_update_dpp(0, m, 0x143, 0xF, 0xF, true)); // row_bcast:31
    return __builtin_amdgcn_readlane(m, 63);
}

// 8-element per-lane sorted run (all fields named -> registers, rule #20 safe)
struct TK {
    unsigned k0, k1, k2, k3, k4, k5, k6, k7;
    int      i0, i1, i2, i3, i4, i5, i6, i7;
};

// Batcher odd-even mergesort, 19 comparators, descending lex (stable via idx)
__device__ __forceinline__ void sort8(TK& s) {
    CE(s.k0, s.i0, s.k1, s.i1); CE(s.k2, s.i2, s.k3, s.i3);
    CE(s.k4, s.i4, s.k5, s.i5); CE(s.k6, s.i6, s.k7, s.i7);
    CE(s.k0, s.i0, s.k2, s.i2); CE(s.k1, s.i1, s.k3, s.i3);
    CE(s.k4, s.i4, s.k6, s.i6); CE(s.k5, s.i5, s.k7, s.i7);
    CE(s.k1, s.i1, s.k2, s.i2); CE(s.k5, s.i5, s.k6, s.i6);
    CE(s.k0, s.i0, s.k4, s.i4); CE(s.k1, s.i1, s.k5, s.i5);
    CE(s.k2, s.i2, s.k6, s.i6); CE(s.k3, s.i3, s.k7, s.i7);
    CE(s.k2, s.i2, s.k4, s.i4); CE(s.k3, s.i3, s.k5, s.i5);
    CE(s.k1, s.i1, s.k2, s.i2); CE(s.k3, s.i3, s.k4, s.i4);
    CE(s.k5, s.i5, s.k6, s.i6);
}

__device__ __forceinline__ TK load8(const float* row, int lane, int abase) {
    const float4 lo = *(const float4*)&row[lane * 8];
    const float4 hi = *(const float4*)&row[lane * 8 + 4];
    TK s;
    s.k0 = __float_as_uint(lo.x); s.k1 = __float_as_uint(lo.y);
    s.k2 = __float_as_uint(lo.z); s.k3 = __float_as_uint(lo.w);
    s.k4 = __float_as_uint(hi.x); s.k5 = __float_as_uint(hi.y);
    s.k6 = __float_as_uint(hi.z); s.k7 = __float_as_uint(hi.w);
    s.i0 = abase + lane * 8; s.i1 = s.i0 + 1; s.i2 = s.i0 + 2; s.i3 = s.i0 + 3;
    s.i4 = s.i0 + 4; s.i5 = s.i0 + 5; s.i6 = s.i0 + 6; s.i7 = s.i0 + 7;
    return s;
}

__device__ __forceinline__ void pop8(TK& s) {
    s.k0 = s.k1; s.i0 = s.i1; s.k1 = s.k2; s.i1 = s.i2;
    s.k2 = s.k3; s.i2 = s.i3; s.k3 = s.k4; s.i3 = s.i4;
    s.k4 = s.k5; s.i4 = s.i5; s.k5 = s.k6; s.i5 = s.i6;
    s.k6 = s.k7; s.i6 = s.i7; s.k7 = 0u;
}

// ---------------------------------------------------------------------------
// Fused A+B, v8: CHUNKF=512 (2 anchors/thread). Halves block count (2112->
// 1088) at identical per-block tournament cost -> ~45% less chip-wide topk
// work (the largest static block), 221 vs 429 candidates/row, half the
// launch/barrier overhead, 160 independent class loads in flight. Math and
// iteration order bit-identical to the R11-verified kernel.
// ---------------------------------------------------------------------------
__global__ __launch_bounds__(256, 2) void fusedAB(
    const float* __restrict__ preds,          // (B, 84, A)
    const float* __restrict__ gt_bboxes,      // (B, G, 4)
    const int*   __restrict__ gt_classes,     // (B, G)
    const float* __restrict__ anchor_points,  // (A, 2)
    float2*      __restrict__ aux_ws,         // (B*A) (mx, rdenom)
    unsigned*    __restrict__ inside32,       // (B*A)
    int*         __restrict__ bestg,          // (B*A)
    float*       __restrict__ candv,          // (B*G, NCHF, 13)
    int*         __restrict__ candi,          // (B*G, NCHF, 13)
    float*       __restrict__ out_sum)        // scalar, zeroed here
{
    __shared__ float sx1[NG], sy1[NG], sx2[NG], sy2[NG], sarea[NG];
    __shared__ int   scls[NG];
    __shared__ __align__(16) float salign[GGRP][CHUNKF];  // 32 KB
    __shared__ __align__(16) float sdist[4][CHUNKF];      // 8 KB

    const int tid   = threadIdx.x;
    const int chunk = blockIdx.x;
    const int b     = blockIdx.y;
    const int abase = chunk * CHUNKF;
    const int aA    = abase + tid;            // anchor 0 of this thread
    const int aB    = aA + 256;               // anchor 1 of this thread
    const bool liveA = (aA < NA);
    const bool liveB = (aB < NA);

    if (tid < NG) {
        const float* gb = gt_bboxes + ((size_t)b * NG + tid) * 4;
        const float x1 = gb[0], y1 = gb[1], x2 = gb[2], y2 = gb[3];
        sx1[tid] = x1; sy1[tid] = y1; sx2[tid] = x2; sy2[tid] = y2;
        sarea[tid] = (x2 - x1) * (y2 - y1);
        scls[tid]  = gt_classes[b * NG + tid];
    }
    if (b == 0 && chunk == 0 && tid == 0) out_sum[0] = 0.0f;

    // ---- stage dist planes cooperatively: 2 float4s per thread ----
#pragma unroll
    for (int i = 0; i < 2; ++i) {
        const int idx = tid + i * 256;          // flat float4 idx 0..511
        const int p = idx >> 7, k = idx & 127;  // plane, float4-in-plane
        float4 v = make_float4(0.0f, 0.0f, 0.0f, 0.0f);
        if (abase + 4 * k < NA)   // NA%4==0 -> clean live/dead split
            v = *(const float4*)(preds + ((size_t)b * (4 + NC) + p) * NA + abase + 4 * k);
        *(float4*)&sdist[p][4 * k] = v;
    }
    __syncthreads();   // also covers sx1../scls writes above

    // ---- per-thread decode, both anchors (bit-identical expressions) ----
    float axA = 0, ayA = 0, x1A = 0, y1A = 0, x2A = 0, y2A = 0, areaA = 0;
    float axB = 0, ayB = 0, x1B = 0, y1B = 0, x2B = 0, y2B = 0, areaB = 0;
    if (liveA) {
        const float2 ap = *(const float2*)(anchor_points + (size_t)aA * 2);
        axA = ap.x; ayA = ap.y;
        const float l = sdist[0][tid], t = sdist[1][tid];
        const float r = sdist[2][tid], bo = sdist[3][tid];
        x1A = axA - l; y1A = ayA - t; x2A = axA + r; y2A = ayA + bo;
        areaA = (x2A - x1A) * (y2A - y1A);
    }
    if (liveB) {
        const float2 ap = *(const float2*)(anchor_points + (size_t)aB * 2);
        axB = ap.x; ayB = ap.y;
        const float l = sdist[0][tid + 256], t = sdist[1][tid + 256];
        const float r = sdist[2][tid + 256], bo = sdist[3][tid + 256];
        x1B = axB - l; y1B = ayB - t; x2B = axB + r; y2B = ayB + bo;
        areaB = (x2B - x1B) * (y2B - y1B);
    }

    const float* cbA = preds + ((size_t)b * (4 + NC) + 4) * NA + aA;
    const float* cbB = cbA + 256;

    // ---- softmax anchor A (max tree exact; pass-2 ascending order) ----
    float clsA[NC];
    if (liveA) {
#pragma unroll
        for (int c = 0; c < NC; ++c) clsA[c] = cbA[(size_t)c * NA];
    } else {
#pragma unroll
        for (int c = 0; c < NC; ++c) clsA[c] = 0.0f;
    }
    float mA0 = clsA[0], mA1 = clsA[1], mA2 = clsA[2], mA3 = clsA[3];
#pragma unroll
    for (int c = 4; c < NC; c += 4) {
        mA0 = fmaxf(mA0, clsA[c]);     mA1 = fmaxf(mA1, clsA[c + 1]);
        mA2 = fmaxf(mA2, clsA[c + 2]); mA3 = fmaxf(mA3, clsA[c + 3]);
    }
    const float mxA = fmaxf(fmaxf(mA0, mA1), fmaxf(mA2, mA3));
    float dA = 0.0f;
#pragma unroll
    for (int c = 0; c < NC; ++c) dA += __expf(clsA[c] - mxA);
    const float rdA = 1.0f / dA;

    // ---- softmax anchor B ----
    float clsB[NC];
    if (liveB) {
#pragma unroll
        for (int c = 0; c < NC; ++c) clsB[c] = cbB[(size_t)c * NA];
    } else {
#pragma unroll
        for (int c = 0; c < NC; ++c) clsB[c] = 0.0f;
    }
    float mB0 = clsB[0], mB1 = clsB[1], mB2 = clsB[2], mB3 = clsB[3];
#pragma unroll
    for (int c = 4; c < NC; c += 4) {
        mB0 = fmaxf(mB0, clsB[c]);     mB1 = fmaxf(mB1, clsB[c + 1]);
        mB2 = fmaxf(mB2, clsB[c + 2]); mB3 = fmaxf(mB3, clsB[c + 3]);
    }
    const float mxB = fmaxf(fmaxf(mB0, mB1), fmaxf(mB2, mB3));
    float dB = 0.0f;
#pragma unroll
    for (int c = 0; c < NC; ++c) dB += __expf(clsB[c] - mxB);
    const float rdB = 1.0f / dB;

    unsigned insA = 0u, insB = 0u;
    int   bgA = 0, bgB = 0;
    float biA = -1.0f, biB = -1.0f;   // strict > keeps first max (jnp.argmax)

    const int lane = tid & 63;
    const int wid  = tid >> 6;

    // ---- 2 groups of 16 g's: compute -> LDS -> per-wave topk ----
    for (int grp = 0; grp < 2; ++grp) {
        float cvlA[GGRP], cvlB[GGRP];
#pragma unroll
        for (int gg = 0; gg < GGRP; ++gg) {
            const int g = grp * GGRP + gg;
            cvlA[gg] = liveA ? cbA[(size_t)scls[g] * NA] : 0.0f;
            cvlB[gg] = liveB ? cbB[(size_t)scls[g] * NA] : 0.0f;
        }
#pragma unroll
        for (int gg = 0; gg < GGRP; ++gg) {
            const int g = grp * GGRP + gg;
            const float bx1 = sx1[g], by1 = sy1[g], bx2 = sx2[g], by2 = sy2[g];
            const float sag = sarea[g];
            {   // anchor A
                const float ltx = fmaxf(x1A, bx1), lty = fmaxf(y1A, by1);
                const float rbx = fminf(x2A, bx2), rby = fminf(y2A, by2);
                const float w = fmaxf(rbx - ltx, 0.0f), h = fmaxf(rby - lty, 0.0f);
                const float inter = w * h;
                const float iou = inter / (areaA + sag - inter + 1e-7f);
                if (iou > biA) { biA = iou; bgA = g; }
                const float cv = __expf(cvlA[gg] - mxA) * rdA;
                const float al = sqrtf(fmaxf(iou, 1e-12f)) * sqrtf(fmaxf(cv, 1e-12f));
                const float dmin = fminf(fminf(axA - bx1, ayA - by1), fminf(bx2 - axA, by2 - ayA));
                if (dmin > 1e-9f) insA |= (1u << g);
                salign[gg][tid] = liveA ? al : 0.0f;   // sentinel 0 < any real al
            }
            {   // anchor B
                const float ltx = fmaxf(x1B, bx1), lty = fmaxf(y1B, by1);
                const float rbx = fminf(x2B, bx2), rby = fminf(y2B, by2);
                const float w = fmaxf(rbx - ltx, 0.0f), h = fmaxf(rby - lty, 0.0f);
                const float inter = w * h;
                const float iou = inter / (areaB + sag - inter + 1e-7f);
                if (iou > biB) { biB = iou; bgB = g; }
                const float cv = __expf(cvlB[gg] - mxB) * rdB;
                const float al = sqrtf(fmaxf(iou, 1e-12f)) * sqrtf(fmaxf(cv, 1e-12f));
                const float dmin = fminf(fminf(axB - bx1, ayB - by1), fminf(bx2 - axB, by2 - ayB));
                if (dmin > 1e-9f) insB |= (1u << g);
                salign[gg][tid + 256] = liveB ? al : 0.0f;
            }
        }
        __syncthreads();

        // topk: wave wid handles gg = wid*4 .. wid*4+3, 4-wide, 8 elems/lane.
        // lane holds 8 CONSECUTIVE anchors -> lane order == index order, so
        // ballot-first-lane = smallest index among tied heads (exact).
        {
            const int gg0 = wid * 4;
            TK sA = load8(&salign[gg0 + 0][0], lane, abase);
            TK sB = load8(&salign[gg0 + 1][0], lane, abase);
            TK sC = load8(&salign[gg0 + 2][0], lane, abase);
            TK sD = load8(&salign[gg0 + 3][0], lane, abase);
            sort8(sA); sort8(sB); sort8(sC); sort8(sD);

            unsigned rvA = 0u, rvB = 0u, rvC = 0u, rvD = 0u;
            int      riA = 0x7FFFFFFF, riB = 0x7FFFFFFF, riC = 0x7FFFFFFF, riD = 0x7FFFFFFF;
#pragma unroll
            for (int r = 0; r < KTOP; ++r) {
                const unsigned mA = (unsigned)wave_max_pos((int)sA.k0);
                const unsigned mB = (unsigned)wave_max_pos((int)sB.k0);
                const unsigned mC = (unsigned)wave_max_pos((int)sC.k0);
                const unsigned mD = (unsigned)wave_max_pos((int)sD.k0);
                const unsigned long long blA = __ballot(sA.k0 == mA);
                const unsigned long long blB = __ballot(sB.k0 == mB);
                const unsigned long long blC = __ballot(sC.k0 == mC);
                const unsigned long long blD = __ballot(sD.k0 == mD);
                const int wA = __ffsll(blA) - 1;
                const int wB = __ffsll(blB) - 1;
                const int wC = __ffsll(blC) - 1;
                const int wD = __ffsll(blD) - 1;
                const int xA = __builtin_amdgcn_readlane(sA.i0, wA);
                const int xB = __builtin_amdgcn_readlane(sB.i0, wB);
                const int xC = __builtin_amdgcn_readlane(sC.i0, wC);
                const int xD = __builtin_amdgcn_readlane(sD.i0, wD);
                if (lane == wA) pop8(sA);
                if (lane == wB) pop8(sB);
                if (lane == wC) pop8(sC);
                if (lane == wD) pop8(sD);
                if (lane == r) {
                    rvA = mA; riA = xA; rvB = mB; riB = xB;
                    rvC = mC; riC = xC; rvD = mD; riD = xD;
                }
            }
            if (lane < KTOP) {
                const int gbase = b * NG + grp * GGRP + gg0;
                const size_t b0 = ((size_t)(gbase + 0) * NCHF + chunk) * KTOP + lane;
                const size_t b1 = ((size_t)(gbase + 1) * NCHF + chunk) * KTOP + lane;
                const size_t b2 = ((size_t)(gbase + 2) * NCHF + chunk) * KTOP + lane;
                const size_t b3 = ((size_t)(gbase + 3) * NCHF + chunk) * KTOP + lane;
                candv[b0] = __uint_as_float(rvA);  candi[b0] = riA;
                candv[b1] = __uint_as_float(rvB);  candi[b1] = riB;
                candv[b2] = __uint_as_float(rvC);  candi[b2] = riC;
                candv[b3] = __uint_as_float(rvD);  candi[b3] = riD;
            }
        }
        __syncthreads();
    }

    if (liveA) {
        const int i = b * NA + aA;
        aux_ws[i] = make_float2(mxA, rdA);
        inside32[i] = insA;
        bestg[i]    = bgA;
    }
    if (liveB) {
        const int i = b * NA + aB;
        aux_ws[i] = make_float2(mxB, rdB);
        inside32[i] = insB;
        bestg[i]    = bgB;
    }
}

// ---------------------------------------------------------------------------
// Merge: one wave per (b,g): merge NCHF*13=221 candidates -> final top-13.
// Lane sees <=4 candidates (ceil(221/64)=4) -> 4-deep sorted list.
// Same DPP lex-max extraction as the HW-verified 7-deep version.
// ---------------------------------------------------------------------------
__global__ __launch_bounds__(256) void mergeTopK(
    const float* __restrict__ candv,
    const int*   __restrict__ candi,
    int*         __restrict__ topk13)   // (B*G, 13)
{
    const int tid  = threadIdx.x;
    const int lane = tid & 63;
    const int row  = blockIdx.x * 4 + (tid >> 6);   // b*NG + g
    const size_t base = (size_t)row * NCAND;

    float v0 = -FLT_MAX, v1 = -FLT_MAX, v2 = -FLT_MAX, v3 = -FLT_MAX;
    int   d0 = 0x7FFFFFFF, d1 = 0x7FFFFFFF, d2 = 0x7FFFFFFF, d3 = 0x7FFFFFFF;

#pragma unroll
    for (int k = 0; k < 4; ++k) {
        const int j0 = lane + 64 * k;
        if (j0 < NCAND) {
            const float x  = candv[base + j0];
            const int   xi = candi[base + j0];
            int r = 0;
            r += (v0 > x) || (v0 == x && d0 < xi);
            r += (v1 > x) || (v1 == x && d1 < xi);
            r += (v2 > x) || (v2 == x && d2 < xi);
            r += (v3 > x) || (v3 == x && d3 < xi);
            v3 = (3 < r) ? v3 : ((3 == r) ? x : v2);  d3 = (3 < r) ? d3 : ((3 == r) ? xi : d2);
            v2 = (2 < r) ? v2 : ((2 == r) ? x : v1);  d2 = (2 < r) ? d2 : ((2 == r) ? xi : d1);
            v1 = (1 < r) ? v1 : ((1 == r) ? x : v0);  d1 = (1 < r) ? d1 : ((1 == r) ? xi : d0);
            v0 = (0 == r) ? x  : v0;                  d0 = (0 == r) ? xi : d0;
        }
    }

    int ri = 0x7FFFFFFF;
#pragma unroll
    for (int rnd = 0; rnd < KTOP; ++rnd) {
        const int hk = __float_as_int(v0);          // head key (signed-monotone)
        const int mk = wave_max_pos(hk);            // wave max value
        // min idx among tied lanes via max over (INT_MAX - idx); losers -1
        const int key2 = (hk == mk) ? (INT_MAX - d0) : -1;
        const int mk2  = wave_max_pos(key2);
        const int midx = INT_MAX - mk2;
        if (hk == mk && d0 == midx) {               // unique winner pops
            v0 = v1; d0 = d1; v1 = v2; d1 = d2; v2 = v3; d2 = d3;
            v3 = -FLT_MAX; d3 = 0x7FFFFFFF;
        }
        if (lane == rnd) ri = midx;
    }
    if (lane < KTOP) topk13[(size_t)row * KTOP + lane] = ri;
}

// ---------------------------------------------------------------------------
// Phase C: grid (33, B), 256-anchor blocks — UNCHANGED from R11-verified.
// ---------------------------------------------------------------------------
__global__ __launch_bounds__(256) void phaseC(
    const float*    __restrict__ gt_bboxes,
    const int*      __restrict__ gt_classes,
    const float*    __restrict__ preds,
    const float*    __restrict__ anchor_points,
    const float2*   __restrict__ aux_ws,
    const int*      __restrict__ topk13,    // (B*G, 13)
    const unsigned* __restrict__ inside32,
    const int*      __restrict__ bestg,
    float*          __restrict__ out)
{
    __shared__ unsigned smask[CHUNK];
    __shared__ float ssum[4];

    const int tid   = threadIdx.x;
    const int b     = blockIdx.y;
    const int abase = blockIdx.x * CHUNK;
    const int a     = abase + tid;

    smask[tid] = 0u;
    __syncthreads();
    for (int j = tid; j < NG * KTOP; j += 256) {
        const int idx = topk13[(size_t)b * NG * KTOP + j];
        const int rel = idx - abase;
        if (rel >= 0 && rel < CHUNK)
            atomicOr(&smask[rel], 1u << (j / KTOP));
    }
    __syncthreads();

    bool fg = false;
    if (a < NA) {
        const int i = b * NA + a;
        unsigned m = smask[tid] & inside32[i];
        const int cnt = __popc(m);

        int tgt;
        if (cnt > 1)       { tgt = bestg[i];     fg = true;  }
        else if (cnt == 1) { tgt = __ffs(m) - 1; fg = true;  }
        else               { tgt = 0;            fg = false; }

        const float f = fg ? 1.0f : 0.0f;
        const float4 gbv = *(const float4*)(gt_bboxes + ((size_t)b * NG + tgt) * 4);
        const float gx1 = gbv.x, gy1 = gbv.y, gx2 = gbv.z, gy2 = gbv.w;
        *(float4*)(out + (size_t)i * 4) = make_float4(gx1 * f, gy1 * f, gx2 * f, gy2 * f);

        const size_t BA = (size_t)NB * NA;
        out[BA * 4 + i] = fg ? (float)gt_classes[b * NG + tgt] : 0.0f;

        float ts = 0.0f;
        if (fg) {
            const float2 ap = *(const float2*)(anchor_points + (size_t)a * 2);
            const float* db = preds + (size_t)b * (4 + NC) * NA + a;
            const float l  = db[0];
            const float t  = db[(size_t)NA];
            const float r  = db[(size_t)2 * NA];
            const float bo = db[(size_t)3 * NA];
            const float x1 = ap.x - l, y1 = ap.y - t, x2 = ap.x + r, y2 = ap.y + bo;
            const float2 ax = aux_ws[i];
            const float areaA = (x2 - x1) * (y2 - y1);
            const float sag   = (gx2 - gx1) * (gy2 - gy1);
            const float ltx = fmaxf(x1, gx1), lty = fmaxf(y1, gy1);
            const float rbx = fminf(x2, gx2), rby = fminf(y2, gy2);
            const float w = fmaxf(rbx - ltx, 0.0f), h = fmaxf(rby - lty, 0.0f);
            const float inter = w * h;
            const float iou = inter / (areaA + sag - inter + 1e-7f);
            const int cls = gt_classes[b * NG + tgt];
            const float cv = __expf(db[(size_t)(4 + cls) * NA] - ax.x) * ax.y;
            ts = sqrtf(fmaxf(iou, 1e-12f)) * sqrtf(fmaxf(cv, 1e-12f));
        }
        out[BA * 5 + i] = ts;
        out[BA * 6 + i] = f;
    }

    const unsigned long long ball = __ballot(fg);
    if ((tid & 63) == 0) ssum[tid >> 6] = (float)__popcll(ball);
    __syncthreads();
    if (tid == 0) {
        const float s = ssum[0] + ssum[1] + ssum[2] + ssum[3];
        if (s != 0.0f) atomicAdd(&out[(size_t)NB * NA * 7], s);
    }
}

// ---------------------------------------------------------------------------
extern "C" void kernel_launch(void* const* d_in, const int* in_sizes, int n_in,
                              void* d_out, int out_size, void* d_ws, size_t ws_size,
                              hipStream_t stream) {
    const float* preds         = (const float*)d_in[0];
    const float* gt_bboxes     = (const float*)d_in[1];
    const int*   gt_classes    = (const int*)  d_in[2];
    const float* anchor_points = (const float*)d_in[3];
    // d_in[4] stride_tensor: unused by the reference math

    float* out = (float*)d_out;
    const size_t BA = (size_t)NB * NA;

    // workspace carve-up: aux | inside | bestg | candv | candi | topk13
    char* ws = (char*)d_ws;
    size_t off = 0;
    float2*   aux_ws   = (float2*)(ws + off);   off += BA * sizeof(float2);
    unsigned* inside32 = (unsigned*)(ws + off); off += BA * sizeof(unsigned);
    int*      bestg    = (int*)(ws + off);      off += BA * sizeof(int);
    float*    candv    = (float*)(ws + off);    off += (size_t)NB * NG * NCAND * sizeof(float);
    int*      candi    = (int*)(ws + off);      off += (size_t)NB * NG * NCAND * sizeof(int);
    int*      topk13   = (int*)(ws + off);

    fusedAB<<<dim3(NCHF, NB), 256, 0, stream>>>(preds, gt_bboxes, gt_classes, anchor_points,
                                                aux_ws, inside32, bestg,
                                                candv, candi, out + BA * 7);

    mergeTopK<<<NB * NG / 4, 256, 0, stream>>>(candv, candi, topk13);

    phaseC<<<dim3(NCH, NB), 256, 0, stream>>>(gt_bboxes, gt_classes, preds, anchor_points,
                                              aux_ws, topk13,
                                              inside32, bestg, out);
}